// Round 1
// baseline (241.954 us; speedup 1.0000x reference)
//
#include <hip/hip_runtime.h>

// Problem constants (32, 3, 384, 640) fp32.
#define BATCH 32
#define CHAN  3
#define HH    384
#define WW    640

__global__ __launch_bounds__(256)
void ssim_l1_kernel(const float* __restrict__ src,
                    const float* __restrict__ tgt,
                    float* __restrict__ out) {
    const int HW = HH * WW;
    int idx = blockIdx.x * 256 + threadIdx.x;
    if (idx >= BATCH * HW) return;

    int w  = idx % WW;
    int bh = idx / WW;
    int h  = bh % HH;
    int b  = bh / HH;

    const float C1v = 6.5025f;    // (0.01*255)^2
    const float C2v = 58.5225f;   // (0.03*255)^2
    const float inv9 = 1.0f / 9.0f;

    // reflect-pad(1) index maps: -1 -> 1, H -> H-2
    int hh[3], ww[3];
#pragma unroll
    for (int i = 0; i < 3; i++) {
        int r = h + i - 1;
        if (r < 0) r = -r;
        if (r >= HH) r = 2 * HH - 2 - r;
        hh[i] = r;
        int q = w + i - 1;
        if (q < 0) q = -q;
        if (q >= WW) q = 2 * WW - 2 - q;
        ww[i] = q;
    }

    float ssim_sum = 0.f, l1_sum = 0.f;

#pragma unroll
    for (int c = 0; c < CHAN; c++) {
        const float* __restrict__ xs = src + (size_t)(b * CHAN + c) * HW;
        const float* __restrict__ ys = tgt + (size_t)(b * CHAN + c) * HW;

        float Sx = 0.f, Sy = 0.f, Sxx = 0.f, Syy = 0.f, Sxy = 0.f;
        float xc = 0.f, yc = 0.f;
#pragma unroll
        for (int i = 0; i < 3; i++) {
            const float* __restrict__ xr = xs + hh[i] * WW;
            const float* __restrict__ yr = ys + hh[i] * WW;
#pragma unroll
            for (int j = 0; j < 3; j++) {
                float x = xr[ww[j]];
                float y = yr[ww[j]];
                if (i == 1 && j == 1) { xc = x; yc = y; }
                Sx += x;
                Sy += y;
                Sxx = fmaf(x, x, Sxx);
                Syy = fmaf(y, y, Syy);
                Sxy = fmaf(x, y, Sxy);
            }
        }

        float mux = Sx * inv9;
        float muy = Sy * inv9;
        float sigx  = Sxx * inv9 - mux;            // faithful: subtracts mu, not mu^2
        float sigy  = Syy * inv9 - muy;
        float sigxy = Sxy * inv9 - mux * muy;

        float num = (2.f * mux * muy + C1v) * (2.f * sigxy + C2v);
        float den = (mux * mux + muy * muy + C1v) * (sigx + sigy + C2v);
        float ns  = 0.5f * (1.f - num / den);
        ns = fminf(fmaxf(ns, 0.f), 1.f);
        ssim_sum += ns;

        l1_sum += fabsf(xc - yc);
    }

    float ssim = ssim_sum * (1.f / 3.f);
    float l1   = l1_sum * (1.f / 3.f);
    out[(size_t)b * HW + h * WW + w] = 0.5f * 0.85f * ssim + 0.15f * l1;
}

extern "C" void kernel_launch(void* const* d_in, const int* in_sizes, int n_in,
                              void* d_out, int out_size, void* d_ws, size_t ws_size,
                              hipStream_t stream) {
    const float* src = (const float*)d_in[0];   // 'output' in reference
    const float* tgt = (const float*)d_in[1];   // 'target'
    float* out = (float*)d_out;

    int total = BATCH * HH * WW;                // 7,864,320
    int blocks = (total + 255) / 256;
    ssim_l1_kernel<<<blocks, 256, 0, stream>>>(src, tgt, out);
}